// Round 1
// baseline (1928.872 us; speedup 1.0000x reference)
//
#include <hip/hip_runtime.h>
#include <cmath>

// Problem constants
#define NN 64
#define CC 96
#define TT 128
#define VV 25
#define SS 3
#define MID 32
#define TCH 4              // t-chunks in kernel A
#define TPER (TT / TCH)    // 32

// LDS row pads (in floats). All row strides are 16B-aligned for float4.
#define XP   100   // xsT rows: [v][c], 96+4      (400B rows)
#define QKP  84    // qkS rows: [v][o], 64+20     (336B rows)
#define VALP 28    // vals rows: [c][v], 25+3     (112B rows)
#define ATTP 28    // attL rows: [s][u][v], 25+3  (112B rows)
#define YSP  100   // ysT rows: [u][c], 96+4      (400B rows)

// joint -> part / body group tables (precomputed from PART_GROUP/BODY_GROUP)
__constant__ int JP[25] = {0,0,1,1,2,2,2,3,4,4,4,5,6,6,7,7,8,8,9,9,0,3,3,5,5};
__constant__ int JB[25] = {4,4,4,4,0,0,0,0,1,1,1,1,2,2,2,2,3,3,3,3,4,0,0,1,1};

// ---------------------------------------------------------------------------
// Kernel A: partial Gram matrices  G[n][s][u][v] (partial over t-chunk)
//   q = W_in rows [s*32, s*32+32) , k = W_in rows [96+s*32, 96+s*32+32)
//   G[u][v] += sum_{c,t} q[c,t,u] * k[c,t,v]
// grid = N*S*TCH blocks, 256 threads
// ---------------------------------------------------------------------------
__global__ __launch_bounds__(256) void kA(
    const float* __restrict__ x, const float* __restrict__ w_in,
    const float* __restrict__ b_in, float* __restrict__ partG)
{
  const int tid = threadIdx.x;
  const int blk = blockIdx.x;              // n*(SS*TCH) + s*TCH + tc
  const int tc  = blk % TCH;
  const int s   = (blk / TCH) % SS;
  const int n   = blk / (TCH * SS);

  __shared__ __align__(16) float xsT[28 * XP];   // [v][c]; rows 25..27 uninit
  __shared__ __align__(16) float qkS[28 * QKP];  // [v][o]; o: 0..31 q, 32..63 k

  // Gram register accumulators: tiles 2u x 2v, 13x13 = 169 tiles
  float g00 = 0.f, g01 = 0.f, g10 = 0.f, g11 = 0.f;
  const bool gact = (tid < 169);
  const int  gut  = tid / 13, gvt = tid % 13;
  const int  gu   = gut * 2,  gv  = gvt * 2;

  const float* xn = x + (size_t)n * CC * TT * VV;

  for (int t = tc * TPER; t < (tc + 1) * TPER; ++t) {
    // stage xsT[v][c]; c-fast so LDS writes are contiguous (conflict-free)
    for (int e = tid; e < VV * CC; e += 256) {
      int v = e / CC, c = e - v * CC;
      xsT[v * XP + c] = xn[((size_t)c * TT + t) * VV + v];
    }
    __syncthreads();

    // q,k phase: 64 outputs (q 0..31, k 32..63) x 28 padded v; tiles 4o x 2v
    if (tid < 224) {
      const int ot = tid / 14, vt2 = tid % 14;
      const int o0 = ot * 4,   v0  = vt2 * 2;
      float a[4][2];
      int row[4];
      #pragma unroll
      for (int i = 0; i < 4; ++i) {
        int o = o0 + i;
        row[i] = (o < MID) ? (s * MID + o) : (CC + s * MID + (o - MID));
        float bb = b_in[row[i]];
        a[i][0] = bb; a[i][1] = bb;
      }
      for (int ck = 0; ck < CC / 4; ++ck) {
        float4 xa = *(const float4*)&xsT[v0 * XP + ck * 4];
        float4 xb = *(const float4*)&xsT[(v0 + 1) * XP + ck * 4];
        #pragma unroll
        for (int i = 0; i < 4; ++i) {
          float4 w = *(const float4*)&w_in[(size_t)row[i] * CC + ck * 4];
          a[i][0] += w.x * xa.x + w.y * xa.y + w.z * xa.z + w.w * xa.w;
          a[i][1] += w.x * xb.x + w.y * xb.y + w.z * xb.z + w.w * xb.w;
        }
      }
      #pragma unroll
      for (int i = 0; i < 4; ++i) {
        qkS[v0 * QKP + o0 + i]       = a[i][0];
        qkS[(v0 + 1) * QKP + o0 + i] = a[i][1];
      }
    }
    __syncthreads();

    // Gram: G[u][v] += sum_c qkS[u][c] * qkS[v][32+c]
    if (gact) {
      for (int ck = 0; ck < MID / 4; ++ck) {
        float4 qa = *(const float4*)&qkS[gu * QKP + ck * 4];
        float4 qb = *(const float4*)&qkS[(gu + 1) * QKP + ck * 4];
        float4 ka = *(const float4*)&qkS[gv * QKP + 32 + ck * 4];
        float4 kb = *(const float4*)&qkS[(gv + 1) * QKP + 32 + ck * 4];
        g00 += qa.x * ka.x + qa.y * ka.y + qa.z * ka.z + qa.w * ka.w;
        g01 += qa.x * kb.x + qa.y * kb.y + qa.z * kb.z + qa.w * kb.w;
        g10 += qb.x * ka.x + qb.y * ka.y + qb.z * ka.z + qb.w * ka.w;
        g11 += qb.x * kb.x + qb.y * kb.y + qb.z * kb.z + qb.w * kb.w;
      }
    }
    __syncthreads();
  }

  // write partials: layout [n][s][tc][25*25] == [blk][625]
  if (gact) {
    float* pg = partG + (size_t)blk * (VV * VV);
    pg[gu * VV + gv] = g00;
    if (gv + 1 < VV) pg[gu * VV + gv + 1] = g01;
    if (gu + 1 < VV) pg[(gu + 1) * VV + gv] = g10;
    if (gu + 1 < VV && gv + 1 < VV) pg[(gu + 1) * VV + gv + 1] = g11;
  }
}

// ---------------------------------------------------------------------------
// Kernel A2: att[n][s][u][v] = tanh(G/4096) + p_att[n,s,jp(u),jp(v)] + b_att[n,s,jb(u),jb(v)]
// grid = N*S blocks
// ---------------------------------------------------------------------------
__global__ __launch_bounds__(256) void kA2(
    const float* __restrict__ partG, const float* __restrict__ p_att,
    const float* __restrict__ b_att, float* __restrict__ att)
{
  const int ns = blockIdx.x;   // n*SS + s
  for (int e = threadIdx.x; e < VV * VV; e += 256) {
    int u = e / VV, v = e - u * VV;
    float g = 0.f;
    #pragma unroll
    for (int tc = 0; tc < TCH; ++tc)
      g += partG[((size_t)ns * TCH + tc) * (VV * VV) + e];
    float a = tanhf(g * (1.0f / (MID * TT)));
    a += p_att[(size_t)ns * 100 + JP[u] * 10 + JP[v]];
    a += b_att[(size_t)ns * 25  + JB[u] * 5  + JB[v]];
    att[(size_t)ns * (VV * VV) + e] = a;
  }
}

// ---------------------------------------------------------------------------
// Kernel B: per (n,t):
//   val = W_in[192:288] x + b_in[192:288]
//   y[c][u] = sum_v att[s(c)][u][v] * val[c][v]
//   out = leaky( x + BN(W_ff y + b_ff) )
// grid = N*T blocks, 256 threads
// ---------------------------------------------------------------------------
__global__ __launch_bounds__(256) void kB(
    const float* __restrict__ x, const float* __restrict__ w_in,
    const float* __restrict__ b_in, const float* __restrict__ w_ff,
    const float* __restrict__ b_ff, const float* __restrict__ bn_gamma,
    const float* __restrict__ bn_beta, const float* __restrict__ bn_mean,
    const float* __restrict__ bn_var, const float* __restrict__ att,
    float* __restrict__ out)
{
  const int tid = threadIdx.x;
  const int blk = blockIdx.x;    // n*TT + t
  const int t = blk % TT, n = blk / TT;

  __shared__ __align__(16) float xsT[28 * XP];            // [v][c]
  __shared__ __align__(16) float vals[CC * VALP];         // [c][v]
  __shared__ __align__(16) float ysT[28 * YSP];           // [u][c]
  __shared__ __align__(16) float attL[(SS * VV + 1) * ATTP]; // [s][u][v] (+1 guard row)

  const float* xn = x + (size_t)n * CC * TT * VV;

  // stage xsT[v][c]
  for (int e = tid; e < VV * CC; e += 256) {
    int v = e / CC, c = e - v * CC;
    xsT[v * XP + c] = xn[((size_t)c * TT + t) * VV + v];
  }
  // stage attL (zero v-pads)
  for (int e = tid; e < SS * VV * ATTP; e += 256) {
    int s = e / (VV * ATTP);
    int r = e - s * (VV * ATTP);
    int u = r / ATTP, v = r - u * ATTP;
    attL[e] = (v < VV) ? att[((size_t)(n * SS + s) * VV + u) * VV + v] : 0.f;
  }
  // zero val v-pads
  for (int e = tid; e < CC * (VALP - VV); e += 256) {
    int c = e / (VALP - VV), j = e - c * (VALP - VV);
    vals[c * VALP + VV + j] = 0.f;
  }
  __syncthreads();

  // VAL phase: tiles 4c x 2v: 24 x 13 = 312
  for (int e = tid; e < 312; e += 256) {
    const int ct = e / 13, vt = e - ct * 13;
    const int c0 = ct * 4, v0 = vt * 2;
    float a[4][2];
    #pragma unroll
    for (int i = 0; i < 4; ++i) {
      float bb = b_in[2 * CC + c0 + i];
      a[i][0] = bb; a[i][1] = bb;
    }
    for (int ck = 0; ck < CC / 4; ++ck) {
      float4 xa = *(const float4*)&xsT[v0 * XP + ck * 4];
      float4 xb = *(const float4*)&xsT[(v0 + 1) * XP + ck * 4];
      #pragma unroll
      for (int i = 0; i < 4; ++i) {
        float4 w = *(const float4*)&w_in[(size_t)(2 * CC + c0 + i) * CC + ck * 4];
        a[i][0] += w.x * xa.x + w.y * xa.y + w.z * xa.z + w.w * xa.w;
        a[i][1] += w.x * xb.x + w.y * xb.y + w.z * xb.z + w.w * xb.w;
      }
    }
    #pragma unroll
    for (int i = 0; i < 4; ++i) {
      vals[(c0 + i) * VALP + v0] = a[i][0];
      if (v0 + 1 < VV) vals[(c0 + i) * VALP + v0 + 1] = a[i][1];
    }
  }
  __syncthreads();

  // Y phase: y[c][u] = sum_v attL[s][u][v]*vals[c][v]; tiles 2c x 2u: 48x13=624
  for (int e = tid; e < 624; e += 256) {
    const int ct = e / 13, ut = e - ct * 13;
    const int c0 = ct * 2, u0 = ut * 2;
    const int s = c0 / MID;
    float a00 = 0.f, a01 = 0.f, a10 = 0.f, a11 = 0.f;
    for (int ck = 0; ck < VALP / 4; ++ck) {
      float4 va = *(const float4*)&vals[c0 * VALP + ck * 4];
      float4 vb = *(const float4*)&vals[(c0 + 1) * VALP + ck * 4];
      float4 ta = *(const float4*)&attL[(s * VV + u0) * ATTP + ck * 4];
      float4 tb = *(const float4*)&attL[(s * VV + u0 + 1) * ATTP + ck * 4];
      a00 += ta.x * va.x + ta.y * va.y + ta.z * va.z + ta.w * va.w;
      a01 += ta.x * vb.x + ta.y * vb.y + ta.z * vb.z + ta.w * vb.w;
      a10 += tb.x * va.x + tb.y * va.y + tb.z * va.z + tb.w * va.w;
      a11 += tb.x * vb.x + tb.y * vb.y + tb.z * vb.z + tb.w * vb.w;
    }
    ysT[u0 * YSP + c0]     = a00;
    ysT[u0 * YSP + c0 + 1] = a01;
    if (u0 + 1 < VV) {
      ysT[(u0 + 1) * YSP + c0]     = a10;
      ysT[(u0 + 1) * YSP + c0 + 1] = a11;
    }
  }
  __syncthreads();

  // FF + BN + residual + leaky: tiles 4o x 2u: 24 x 13 = 312
  for (int e = tid; e < 312; e += 256) {
    const int ot = e / 13, ut = e - ot * 13;
    const int o0 = ot * 4, u0 = ut * 2;
    float a[4][2];
    #pragma unroll
    for (int i = 0; i < 4; ++i) {
      float bb = b_ff[o0 + i];
      a[i][0] = bb; a[i][1] = bb;
    }
    for (int ck = 0; ck < CC / 4; ++ck) {
      float4 ya = *(const float4*)&ysT[u0 * YSP + ck * 4];
      float4 yb = *(const float4*)&ysT[(u0 + 1) * YSP + ck * 4];
      #pragma unroll
      for (int i = 0; i < 4; ++i) {
        float4 w = *(const float4*)&w_ff[(size_t)(o0 + i) * CC + ck * 4];
        a[i][0] += w.x * ya.x + w.y * ya.y + w.z * ya.z + w.w * ya.w;
        a[i][1] += w.x * yb.x + w.y * yb.y + w.z * yb.z + w.w * yb.w;
      }
    }
    #pragma unroll
    for (int i = 0; i < 4; ++i) {
      const int o = o0 + i;
      const float inv  = bn_gamma[o] * rsqrtf(bn_var[o] + 1e-5f);
      const float mean = bn_mean[o], beta = bn_beta[o];
      #pragma unroll
      for (int j = 0; j < 2; ++j) {
        const int u = u0 + j;
        if (u < VV) {
          float z = (a[i][j] - mean) * inv + beta + xsT[u * XP + o];
          out[((size_t)(n * CC + o) * TT + t) * VV + u] = (z >= 0.f) ? z : 0.1f * z;
        }
      }
    }
  }
}

// ---------------------------------------------------------------------------
extern "C" void kernel_launch(void* const* d_in, const int* in_sizes, int n_in,
                              void* d_out, int out_size, void* d_ws, size_t ws_size,
                              hipStream_t stream)
{
  const float* x     = (const float*)d_in[0];
  const float* p_att = (const float*)d_in[1];
  const float* b_att = (const float*)d_in[2];
  const float* w_in  = (const float*)d_in[3];
  const float* b_in  = (const float*)d_in[4];
  const float* w_ff  = (const float*)d_in[5];
  const float* b_ff  = (const float*)d_in[6];
  const float* gam   = (const float*)d_in[7];
  const float* bet   = (const float*)d_in[8];
  const float* mea   = (const float*)d_in[9];
  const float* var   = (const float*)d_in[10];
  float* out = (float*)d_out;

  float* partG = (float*)d_ws;                                  // 768*625 floats
  float* att   = partG + (size_t)NN * SS * TCH * VV * VV;       // 192*625 floats

  kA <<<NN * SS * TCH, 256, 0, stream>>>(x, w_in, b_in, partG);
  kA2<<<NN * SS,       256, 0, stream>>>(partG, p_att, b_att, att);
  kB <<<NN * TT,       256, 0, stream>>>(x, w_in, b_in, w_ff, b_ff,
                                         gam, bet, mea, var, att, out);
}

// Round 2
// 116.969 us; speedup vs baseline: 16.4905x; 16.4905x over previous
//
#include <hip/hip_runtime.h>
#include <cmath>

#define NN 64
#define CC 96
#define TT 128
#define VV 25
#define SS 3
#define TB 4
#define NTB (TT/TB)          /* 32 */
#define ROWS (TB*VV)         /* 100 */
#define XTP 104              /* xT row pad (bf16 elems), 208B rows */
#define XTROWS 112
#define QKP 200              /* qk row pad, 400B rows */
#define QKROWS 112
#define VALP 40              /* val row pad, 80B rows */
#define YLP 104              /* y row pad, 208B rows */

typedef __attribute__((ext_vector_type(8))) __bf16 bf16x8;
typedef __attribute__((ext_vector_type(4))) float f32x4;

#define MFMA16(a,b,c) __builtin_amdgcn_mfma_f32_16x16x32_bf16((a),(b),(c),0,0,0)

__constant__ int JP[25] = {0,0,1,1,2,2,2,3,4,4,4,5,6,6,7,7,8,8,9,9,0,3,3,5,5};
__constant__ int JB[25] = {4,4,4,4,0,0,0,0,1,1,1,1,2,2,2,2,3,3,3,3,4,0,0,1,1};

__device__ inline unsigned short f2b(float f) {
  unsigned int u = __float_as_uint(f);
  u += 0x7fffu + ((u >> 16) & 1u);
  return (unsigned short)(u >> 16);
}
__device__ inline float b2f(unsigned short h) {
  return __uint_as_float(((unsigned int)h) << 16);
}
__device__ inline bf16x8 ldbf8(const unsigned short* p) {
  union { uint4 u; bf16x8 b; } z;
  z.u = *(const uint4*)p;
  return z.b;
}
__device__ inline f32x4 fz() {
  f32x4 z; z[0] = 0.f; z[1] = 0.f; z[2] = 0.f; z[3] = 0.f; return z;
}

// ---------------------------------------------------------------------------
// k0: convert weights to bf16 in ws
// ---------------------------------------------------------------------------
__global__ __launch_bounds__(256) void k0(
    const float* __restrict__ w_in, const float* __restrict__ w_ff,
    unsigned short* __restrict__ wbin, unsigned short* __restrict__ wbff)
{
  int i = blockIdx.x * 256 + threadIdx.x;
  if (i < 288 * 96) wbin[i] = f2b(w_in[i]);
  if (i < 96 * 96)  wbff[i] = f2b(w_ff[i]);
}

// ---------------------------------------------------------------------------
// k1: per (n, tb): QK GEMM (MFMA) -> Gram partials
// ---------------------------------------------------------------------------
__global__ __launch_bounds__(256, 2) void k1(
    const float* __restrict__ x, const unsigned short* __restrict__ wbin,
    const float* __restrict__ b_in, float* __restrict__ partG)
{
  __shared__ unsigned short xT[XTROWS * XTP];   // [i=dt*25+v][c] bf16
  __shared__ unsigned short qk[QKROWS * QKP];   // [i=dt*25+v][o 0..191] bf16
  __shared__ float bL[192];

  const int tid  = threadIdx.x;
  const int wid  = tid >> 6, lane = tid & 63;
  const int lrow = lane & 15;
  const int lk8  = (lane >> 4) << 3;
  const int ldr4 = (lane >> 4) << 2;
  const int tb = blockIdx.x & (NTB - 1);
  const int n  = blockIdx.x >> 5;
  const int t0 = tb * TB;

  // stage xT: x[n,c,t0+dt,v] -> xT[dt*25+v][c]; global reads contiguous in i
  const float* xb = x + (size_t)n * CC * TT * VV + (size_t)t0 * VV;
  for (int e = tid; e < CC * ROWS; e += 256) {
    int c = e / ROWS, i = e - c * ROWS;
    xT[i * XTP + c] = f2b(xb[(size_t)c * TT * VV + i]);
  }
  if (tid < 192) bL[tid] = b_in[tid];
  __syncthreads();

  // QK GEMM: D[o=0..191][col=0..111] ; wave handles mf = 3*wid..3*wid+2
  f32x4 acc[3][7];
  #pragma unroll
  for (int i = 0; i < 3; ++i)
    #pragma unroll
    for (int nf = 0; nf < 7; ++nf) acc[i][nf] = fz();

  #pragma unroll
  for (int ks = 0; ks < 3; ++ks) {
    bf16x8 a[3];
    #pragma unroll
    for (int i = 0; i < 3; ++i)
      a[i] = ldbf8(&wbin[((wid * 3 + i) * 16 + lrow) * 96 + ks * 32 + lk8]);
    #pragma unroll
    for (int nf = 0; nf < 7; ++nf) {
      bf16x8 b = ldbf8(&xT[(nf * 16 + lrow) * XTP + ks * 32 + lk8]);
      #pragma unroll
      for (int i = 0; i < 3; ++i)
        acc[i][nf] = MFMA16(a[i], b, acc[i][nf]);
    }
  }
  // bias + bf16 + store to qk[col][o] (4 consecutive o per lane -> ushort4)
  #pragma unroll
  for (int i = 0; i < 3; ++i) {
    int ob = (wid * 3 + i) * 16 + ldr4;
    float4 bb = *(const float4*)&bL[ob];
    #pragma unroll
    for (int nf = 0; nf < 7; ++nf) {
      int col = nf * 16 + lrow;
      ushort4 h;
      h.x = f2b(acc[i][nf][0] + bb.x);
      h.y = f2b(acc[i][nf][1] + bb.y);
      h.z = f2b(acc[i][nf][2] + bb.z);
      h.w = f2b(acc[i][nf][3] + bb.w);
      *(ushort4*)&qk[col * QKP + ob] = h;
    }
  }
  __syncthreads();

  // Gram: waves 0..2, s = wid. G[u][v] += sum_{dt,cm} q[dt,u,cm]*k[dt,v,cm]
  if (wid < 3) {
    const int s = wid;
    f32x4 g[2][2];
    g[0][0] = fz(); g[0][1] = fz(); g[1][0] = fz(); g[1][1] = fz();
    #pragma unroll
    for (int dt = 0; dt < TB; ++dt) {
      int r0 = dt * VV;
      bf16x8 a0 = ldbf8(&qk[(r0 + lrow) * QKP + s * 32 + lk8]);
      bf16x8 a1 = ldbf8(&qk[(r0 + 16 + lrow) * QKP + s * 32 + lk8]);
      bf16x8 b0 = ldbf8(&qk[(r0 + lrow) * QKP + 96 + s * 32 + lk8]);
      bf16x8 b1 = ldbf8(&qk[(r0 + 16 + lrow) * QKP + 96 + s * 32 + lk8]);
      g[0][0] = MFMA16(a0, b0, g[0][0]);
      g[0][1] = MFMA16(a0, b1, g[0][1]);
      g[1][0] = MFMA16(a1, b0, g[1][0]);
      g[1][1] = MFMA16(a1, b1, g[1][1]);
    }
    float* pg = partG + ((size_t)(n * SS + s) * NTB + tb) * (VV * VV);
    #pragma unroll
    for (int mi = 0; mi < 2; ++mi)
      #pragma unroll
      for (int ni = 0; ni < 2; ++ni)
        #pragma unroll
        for (int r = 0; r < 4; ++r) {
          int u = mi * 16 + ldr4 + r, v = ni * 16 + lrow;
          if (u < VV && v < VV) pg[u * VV + v] = g[mi][ni][r];
        }
  }
}

// ---------------------------------------------------------------------------
// k2: reduce partials, tanh + positional gathers -> att bf16 [ns][32][32]
// ---------------------------------------------------------------------------
__global__ __launch_bounds__(256) void k2(
    const float* __restrict__ partG, const float* __restrict__ p_att,
    const float* __restrict__ b_att, unsigned short* __restrict__ att)
{
  const int ns = blockIdx.x;
  for (int e = threadIdx.x; e < 1024; e += 256) {
    int u = e >> 5, v = e & 31;
    float a = 0.f;
    if (u < VV && v < VV) {
      float g = 0.f;
      const float* pg = partG + (size_t)ns * NTB * (VV * VV) + u * VV + v;
      for (int tb = 0; tb < NTB; ++tb) g += pg[tb * VV * VV];
      a = tanhf(g * (1.0f / 4096.0f))
        + p_att[(size_t)ns * 100 + JP[u] * 10 + JP[v]]
        + b_att[(size_t)ns * 25  + JB[u] * 5  + JB[v]];
    }
    att[(size_t)ns * 1024 + e] = f2b(a);
  }
}

// ---------------------------------------------------------------------------
// k3: per (n, tb): VAL GEMM -> PV (att) -> FF GEMM -> BN + residual + leaky
// ---------------------------------------------------------------------------
__global__ __launch_bounds__(256, 2) void k3(
    const float* __restrict__ x, const unsigned short* __restrict__ wbin,
    const unsigned short* __restrict__ wbff,
    const float* __restrict__ b_in, const float* __restrict__ b_ff,
    const float* __restrict__ gam, const float* __restrict__ bet,
    const float* __restrict__ mea, const float* __restrict__ var,
    const unsigned short* __restrict__ att, float* __restrict__ out)
{
  __shared__ unsigned short xT[XTROWS * XTP];   // 23296 B
  __shared__ unsigned short val[384 * VALP];    // 30720 B ; yL overlays after PV
  __shared__ float scL[96], shL[96], bvL[96];

  const int tid  = threadIdx.x;
  const int wid  = tid >> 6, lane = tid & 63;
  const int lrow = lane & 15;
  const int lk8  = (lane >> 4) << 3;
  const int ldr4 = (lane >> 4) << 2;
  const int tb = blockIdx.x & (NTB - 1);
  const int n  = blockIdx.x >> 5;
  const int t0 = tb * TB;

  const float* xb = x + (size_t)n * CC * TT * VV + (size_t)t0 * VV;
  for (int e = tid; e < CC * ROWS; e += 256) {
    int c = e / ROWS, i = e - c * ROWS;
    xT[i * XTP + c] = f2b(xb[(size_t)c * TT * VV + i]);
  }
  for (int e = tid; e < (384 * VALP) / 2; e += 256)
    ((unsigned int*)val)[e] = 0u;
  if (tid < 96) {
    float sc = gam[tid] * rsqrtf(var[tid] + 1e-5f);
    scL[tid] = sc;
    shL[tid] = (b_ff[tid] - mea[tid]) * sc + bet[tid];
    bvL[tid] = b_in[192 + tid];
  }
  __syncthreads();

  // VAL GEMM: D[c=0..95][col=0..111]; wave handles nf = 2*wid .. min(+1,6)
  for (int nf = wid * 2; nf < 7 && nf < wid * 2 + 2; ++nf) {
    f32x4 acc[6];
    #pragma unroll
    for (int mf = 0; mf < 6; ++mf) acc[mf] = fz();
    #pragma unroll
    for (int ks = 0; ks < 3; ++ks) {
      bf16x8 b = ldbf8(&xT[(nf * 16 + lrow) * XTP + ks * 32 + lk8]);
      #pragma unroll
      for (int mf = 0; mf < 6; ++mf) {
        bf16x8 a = ldbf8(&wbin[(192 + mf * 16 + lrow) * 96 + ks * 32 + lk8]);
        acc[mf] = MFMA16(a, b, acc[mf]);
      }
    }
    int col = nf * 16 + lrow;
    if (col < ROWS) {
      int dt = col / VV, v = col - dt * VV;
      #pragma unroll
      for (int mf = 0; mf < 6; ++mf)
        #pragma unroll
        for (int r = 0; r < 4; ++r) {
          int c = mf * 16 + ldr4 + r;
          val[(dt * 96 + c) * VALP + v] = f2b(acc[mf][r] + bvL[c]);
        }
    }
  }
  __syncthreads();

  // PV: per s: D[u][col=dt*32+cm]; wave handles colfrags {2w, 2w+1}
  const unsigned short* attn = att + (size_t)(n * SS) * 1024;
  f32x4 y[3][2][2];
  #pragma unroll
  for (int s = 0; s < 3; ++s)
    #pragma unroll
    for (int mi = 0; mi < 2; ++mi)
      #pragma unroll
      for (int ci = 0; ci < 2; ++ci) y[s][mi][ci] = fz();

  #pragma unroll
  for (int s = 0; s < 3; ++s) {
    bf16x8 b[2];
    #pragma unroll
    for (int ci = 0; ci < 2; ++ci) {
      int col = (wid * 2 + ci) * 16 + lrow;   // 0..127
      int dt = col >> 5, cm = col & 31;
      b[ci] = ldbf8(&val[(dt * 96 + s * 32 + cm) * VALP + lk8]);
    }
    #pragma unroll
    for (int mi = 0; mi < 2; ++mi) {
      bf16x8 a = ldbf8(&attn[(size_t)s * 1024 + (mi * 16 + lrow) * 32 + lk8]);
      #pragma unroll
      for (int ci = 0; ci < 2; ++ci)
        y[s][mi][ci] = MFMA16(a, b[ci], y[s][mi][ci]);
    }
  }
  __syncthreads();

  // y -> yL[dt*25+u][c] (overlay val)
  unsigned short* yL = val;
  #pragma unroll
  for (int s = 0; s < 3; ++s)
    #pragma unroll
    for (int mi = 0; mi < 2; ++mi)
      #pragma unroll
      for (int ci = 0; ci < 2; ++ci) {
        int col = (wid * 2 + ci) * 16 + lrow;
        int dt = col >> 5, cm = col & 31;
        int c = s * 32 + cm;
        #pragma unroll
        for (int r = 0; r < 4; ++r) {
          int u = mi * 16 + ldr4 + r;
          if (u < VV) yL[(dt * VV + u) * YLP + c] = f2b(y[s][mi][ci][r]);
        }
      }
  __syncthreads();

  // FF GEMM + epilogue
  for (int nf = wid * 2; nf < 7 && nf < wid * 2 + 2; ++nf) {
    f32x4 acc[6];
    #pragma unroll
    for (int mf = 0; mf < 6; ++mf) acc[mf] = fz();
    #pragma unroll
    for (int ks = 0; ks < 3; ++ks) {
      bf16x8 b = ldbf8(&yL[(nf * 16 + lrow) * YLP + ks * 32 + lk8]);
      #pragma unroll
      for (int mf = 0; mf < 6; ++mf) {
        bf16x8 a = ldbf8(&wbff[(mf * 16 + lrow) * 96 + ks * 32 + lk8]);
        acc[mf] = MFMA16(a, b, acc[mf]);
      }
    }
    int i = nf * 16 + lrow;
    if (i < ROWS) {
      int dt = i / VV, u = i - dt * VV;
      int t = t0 + dt;
      #pragma unroll
      for (int mf = 0; mf < 6; ++mf) {
        int o0 = mf * 16 + ldr4;
        ushort4 xr = *(const ushort4*)&xT[i * XTP + o0];
        float4 sc = *(const float4*)&scL[o0];
        float4 sh = *(const float4*)&shL[o0];
        float zr[4];
        zr[0] = acc[mf][0] * sc.x + sh.x + b2f(xr.x);
        zr[1] = acc[mf][1] * sc.y + sh.y + b2f(xr.y);
        zr[2] = acc[mf][2] * sc.z + sh.z + b2f(xr.z);
        zr[3] = acc[mf][3] * sc.w + sh.w + b2f(xr.w);
        #pragma unroll
        for (int r = 0; r < 4; ++r) {
          float z = zr[r];
          z = (z >= 0.f) ? z : 0.1f * z;
          out[((size_t)(n * CC + o0 + r) * TT + t) * VV + u] = z;
        }
      }
    }
  }
}

// ---------------------------------------------------------------------------
extern "C" void kernel_launch(void* const* d_in, const int* in_sizes, int n_in,
                              void* d_out, int out_size, void* d_ws, size_t ws_size,
                              hipStream_t stream)
{
  const float* x     = (const float*)d_in[0];
  const float* p_att = (const float*)d_in[1];
  const float* b_att = (const float*)d_in[2];
  const float* w_in  = (const float*)d_in[3];
  const float* b_in  = (const float*)d_in[4];
  const float* w_ff  = (const float*)d_in[5];
  const float* b_ff  = (const float*)d_in[6];
  const float* gam   = (const float*)d_in[7];
  const float* bet   = (const float*)d_in[8];
  const float* mea   = (const float*)d_in[9];
  const float* var   = (const float*)d_in[10];
  float* out = (float*)d_out;

  char* ws = (char*)d_ws;
  unsigned short* wbin = (unsigned short*)ws;            // 288*96
  unsigned short* wbff = wbin + 288 * 96;                // 96*96
  unsigned short* attw = wbff + 96 * 96;                 // 192*1024
  float* partG = (float*)(ws + 466944);                  // 192*32*625 f32

  k0<<<108, 256, 0, stream>>>(w_in, w_ff, wbin, wbff);
  k1<<<NN * NTB, 256, 0, stream>>>(x, wbin, b_in, partG);
  k2<<<NN * SS, 256, 0, stream>>>(partG, p_att, b_att, attw);
  k3<<<NN * NTB, 256, 0, stream>>>(x, wbin, wbff, b_in, b_ff,
                                   gam, bet, mea, var, attw, out);
}